// Round 2
// baseline (32.380 us; speedup 1.0000x reference)
//
#include <hip/hip_runtime.h>

// Problem constants (from reference): B,D,K,CI,CO,L,NB,P,S = 4,32,8,2,2,4096,15,7,8
constexpr int Bc  = 4;
constexpr int Dc  = 32;
constexpr int Kc  = 8;
constexpr int CIc = 2;
constexpr int COc = 2;
constexpr int Lc  = 4096;
constexpr int NBc = 15;
constexpr int Pc  = 7;
constexpr int Sc  = 8;

constexpr int TILE     = 1024;   // l positions per block
constexpr int NTHREADS = 256;    // each thread: 4 consecutive l, both co
constexpr int WELEMS   = COc * CIc * Sc * NBc;  // 480 weights per (d,k)

// seg(l): first 7 segments are 499 wide, last is 603 -> min(l/499, 7)
__device__ __forceinline__ int seg_of(int l) {
    int s = l / 499;
    return s > 7 ? 7 : s;
}

__global__ __launch_bounds__(NTHREADS) void cde_bcr_kernel(
    const float* __restrict__ x,     // [B][D][K][CI][L]
    const float* __restrict__ w,     // [D][K][CO][CI][S][1][NB]
    const float* __restrict__ bias,  // [D][K][CO][S][1]
    float* __restrict__ out)         // [B][D][K][CO][L]
{
    // xs index = (l - lbase) + 8; interior occupies [8, 8+TILE), halos in [0,8) and [8+TILE, 8+TILE+8)
    __shared__ __align__(16) float xs[CIc][TILE + 16];
    __shared__ __align__(16) float wl[COc * CIc * Sc][16]; // row r=(o*CI+i)*S+s, f padded 15->16
    __shared__ float bl[COc * Sc];

    const int tid   = threadIdx.x;
    const int lbase = blockIdx.x * TILE;
    const int bdk   = blockIdx.y;            // ((b*D + d)*K + k)
    const int dk    = bdk % (Dc * Kc);

    // ---- stage weights (480 floats, grid-stride over 256 threads) + bias (16) ----
    for (int t = tid; t < WELEMS; t += NTHREADS) {
        wl[t / NBc][t % NBc] = w[(size_t)dk * WELEMS + t];
    }
    if (tid < COc * Sc) {
        bl[tid] = bias[(size_t)dk * (COc * Sc) + tid];
    }

    // ---- stage x interior: 2 ci rows of TILE floats, aligned float4 ----
    const float* xb = x + (size_t)bdk * CIc * Lc;
#pragma unroll
    for (int i = 0; i < CIc; ++i) {
        float4 v = *(const float4*)(xb + (size_t)i * Lc + lbase + tid * 4);
        *(float4*)&xs[i][8 + tid * 4] = v;
    }
    // ---- halos: left idx [0,8) <- l in [lbase-8, lbase), right idx [8+TILE, 8+TILE+8) ----
    if (tid < 2 * CIc * 8) {
        int which = tid / (CIc * 8);         // 0 = left, 1 = right
        int rem   = tid % (CIc * 8);
        int i = rem / 8, e = rem % 8;
        int idx = which ? (8 + TILE + e) : e;
        int l   = lbase + (which ? (TILE + e) : (e - 8));
        float v = (l >= 0 && l < Lc) ? xb[(size_t)i * Lc + l] : 0.0f;
        xs[i][idx] = v;
    }
    __syncthreads();

    const int l0  = tid * 4;
    const int gl0 = lbase + l0;
    const int s0  = seg_of(gl0);
    const int s3  = seg_of(gl0 + 3);

    float acc[COc][4];

    if (s0 == s3) {
        // fast path: segment uniform across this thread's 4 outputs
#pragma unroll
        for (int o = 0; o < COc; ++o)
#pragma unroll
            for (int j = 0; j < 4; ++j)
                acc[o][j] = bl[o * Sc + s0];

#pragma unroll
        for (int i = 0; i < CIc; ++i) {
            // x window: xs idx [l0, l0+20) covers all needed (j+f+1 in [1,18])
            float xa[20];
#pragma unroll
            for (int m = 0; m < 5; ++m)
                *(float4*)&xa[m * 4] = *(const float4*)&xs[i][l0 + m * 4];
            // weights for (o=0,i,s0) and (o=1,i,s0): 15 floats each (16th padded, unused)
            float w0[16], w1[16];
#pragma unroll
            for (int m = 0; m < 4; ++m) {
                *(float4*)&w0[m * 4] = *(const float4*)&wl[(0 * CIc + i) * Sc + s0][m * 4];
                *(float4*)&w1[m * 4] = *(const float4*)&wl[(1 * CIc + i) * Sc + s0][m * 4];
            }
#pragma unroll
            for (int f = 0; f < NBc; ++f) {
                float wa = w0[f];
                float wb = w1[f];
#pragma unroll
                for (int j = 0; j < 4; ++j) {
                    float xv = xa[j + f + 1];
                    acc[0][j] = fmaf(wa, xv, acc[0][j]);
                    acc[1][j] = fmaf(wb, xv, acc[1][j]);
                }
            }
        }
    } else {
        // slow path: thread straddles a segment boundary (rare: ~0.7% of threads)
#pragma unroll
        for (int j = 0; j < 4; ++j) {
            int sj = seg_of(gl0 + j);
#pragma unroll
            for (int o = 0; o < COc; ++o)
                acc[o][j] = bl[o * Sc + sj];
#pragma unroll
            for (int i = 0; i < CIc; ++i)
#pragma unroll
                for (int f = 0; f < NBc; ++f) {
                    float xv = xs[i][l0 + j + f + 1];
                    acc[0][j] = fmaf(wl[(0 * CIc + i) * Sc + sj][f], xv, acc[0][j]);
                    acc[1][j] = fmaf(wl[(1 * CIc + i) * Sc + sj][f], xv, acc[1][j]);
                }
        }
    }

    // ---- store: 2 coalesced float4 stores ----
    float* ob = out + (size_t)bdk * COc * Lc + lbase + l0;
    *(float4*)&ob[0]  = make_float4(acc[0][0], acc[0][1], acc[0][2], acc[0][3]);
    *(float4*)&ob[Lc] = make_float4(acc[1][0], acc[1][1], acc[1][2], acc[1][3]);
}

extern "C" void kernel_launch(void* const* d_in, const int* in_sizes, int n_in,
                              void* d_out, int out_size, void* d_ws, size_t ws_size,
                              hipStream_t stream) {
    const float* x    = (const float*)d_in[0];
    const float* w    = (const float*)d_in[1];
    const float* bias = (const float*)d_in[2];
    float* out        = (float*)d_out;

    dim3 grid(Lc / TILE, Bc * Dc * Kc);   // 4 x 1024 blocks
    cde_bcr_kernel<<<grid, NTHREADS, 0, stream>>>(x, w, bias, out);
}